// Round 5
// baseline (229.340 us; speedup 1.0000x reference)
//
#include <hip/hip_runtime.h>
#include <stdint.h>

#define MAX_ITERS 20
#define EPSV 1e-7f
#define CLIPV 1e-7f
#define PI_F 3.14159265358979f
#define PIO2_F 1.57079632679490f

typedef __attribute__((ext_vector_type(8))) short short8;
typedef __attribute__((ext_vector_type(4))) float f4;

__device__ __forceinline__ f4 mfma_bf16(short8 a, short8 b, f4 c) {
    return __builtin_amdgcn_mfma_f32_16x16x32_bf16(a, b, c, 0, 0, 0);
}

__device__ __forceinline__ float rl(float v, int l) {
    return __int_as_float(__builtin_amdgcn_readlane(__float_as_int(v), l));
}

// DPP-routed add: v += v[lane ^ k], VALU pipe (no LDS/bpermute latency)
template <int CTRL>
__device__ __forceinline__ float dpp_add(float v) {
    int p = __builtin_amdgcn_update_dpp(0, __float_as_int(v), CTRL, 0xF, 0xF, true);
    return v + __int_as_float(p);
}

// Sum over rows 0..31 (lanes 32-63 hold duplicates). Wave-uniform result.
__device__ __forceinline__ float rowsum32(float v) {
    v = dpp_add<0xB1>(v);   // quad_perm(1,0,3,2)  == xor1
    v = dpp_add<0x4E>(v);   // quad_perm(2,3,0,1)  == xor2
    v = dpp_add<0x141>(v);  // row_half_mirror     == xor4
    v = dpp_add<0x140>(v);  // row_mirror          == xor8
    return rl(v, 0) + rl(v, 16);
}

// Branchless acos, |err| ~1e-7; input pre-clipped to (-1, 1).
__device__ __forceinline__ float fast_acos(float x) {
    float a = fabsf(x);
    bool big = a > 0.5f;
    float z = big ? 0.5f * (1.0f - a) : x * x;
    float s = big ? sqrtf(z) : x;
    float p = fmaf(z, fmaf(z, fmaf(z, fmaf(z, 4.2163199048e-2f, 2.4181311049e-2f),
                                   4.5470025998e-2f), 7.4953002686e-2f),
                   1.6666752422e-1f);
    float r = fmaf(s * z, p, s);    // asin(s), |s| <= 0.5
    float big_val = (x < 0.0f) ? (PI_F - 2.0f * r) : (2.0f * r);
    return big ? big_val : (PIO2_F - r);
}

// split 8 fp32 -> truncated-bf16 hi + bf16(lo) residual
__device__ __forceinline__ void cvt_hilo(const float* v, short8& hi, short8& lo) {
#pragma unroll
    for (int i = 0; i < 8; ++i) {
        float x = v[i];
        uint32_t u = __float_as_uint(x);
        float hf = __uint_as_float(u & 0xFFFF0000u);
        float lf = x - hf;
        hi[i] = (short)(u >> 16);
        lo[i] = (short)(__float_as_uint(lf) >> 16);
    }
}

// 128 threads = 2 waves/block, one group per wave. LDS 8.4 KB -> ~16 blocks/CU
// (~31 waves/CU resident), vs 35% occupancy with the R4 4-wave/17.9KB shape.
__global__ void __launch_bounds__(128) karcher(const float* __restrict__ X,
                                               float* __restrict__ ws,
                                               int n_groups) {
    __shared__ float sG[2][32 * 33];   // raw Gram, stride-33 (conflict-free rows)

    const int lane = threadIdx.x & 63;
    const int wid  = threadIdx.x >> 6;
    const int g    = blockIdx.x * 2 + wid;   // 8000 % 2 == 0: always valid

    const float* Xg = X + (size_t)g * (32 * 128);
    const int col  = lane & 15;
    const int quad = lane >> 4;

    // ---- Phase 1: raw Gram = X X^T via MFMA, hi/lo bf16 split (err ~1e-5) ---
    f4 acc00 = {0.f, 0.f, 0.f, 0.f};
    f4 acc01 = acc00, acc10 = acc00, acc11 = acc00;
#pragma unroll
    for (int kc = 0; kc < 4; ++kc) {
        const float* p0 = Xg + col * 128 + kc * 32 + quad * 8;
        const float* p1 = p0 + 16 * 128;
        float r0[8], r1[8];
        *(float4*)(r0)     = *(const float4*)(p0);
        *(float4*)(r0 + 4) = *(const float4*)(p0 + 4);
        *(float4*)(r1)     = *(const float4*)(p1);
        *(float4*)(r1 + 4) = *(const float4*)(p1 + 4);
        short8 H0, L0, H1, L1;
        cvt_hilo(r0, H0, L0);
        cvt_hilo(r1, H1, L1);
        acc00 = mfma_bf16(H0, H0, acc00);
        acc00 = mfma_bf16(H0, L0, acc00);
        acc00 = mfma_bf16(L0, H0, acc00);
        acc01 = mfma_bf16(H0, H1, acc01);
        acc01 = mfma_bf16(H0, L1, acc01);
        acc01 = mfma_bf16(L0, H1, acc01);
        acc10 = mfma_bf16(H1, H0, acc10);
        acc10 = mfma_bf16(H1, L0, acc10);
        acc10 = mfma_bf16(L1, H0, acc10);
        acc11 = mfma_bf16(H1, H1, acc11);
        acc11 = mfma_bf16(H1, L1, acc11);
        acc11 = mfma_bf16(L1, H1, acc11);
    }

    float* Gw = sG[wid];
#pragma unroll
    for (int i = 0; i < 4; ++i) {   // C/D: col=lane&15, row=quad*4+i (G sym)
        int rw = quad * 4 + i;
        Gw[rw * 33 + col]             = acc00[i];
        Gw[rw * 33 + col + 16]        = acc01[i];
        Gw[(rw + 16) * 33 + col]      = acc10[i];
        Gw[(rw + 16) * 33 + col + 16] = acc11[i];
    }
    __syncthreads();

    // ---- Phase 2: raw Gram row + own inverse norm (NO cross-lane stage) -----
    // Track alpha' = D*alpha (coeffs wrt raw X); dots_r = inv_r * (G alpha')_r.
    const int r = lane & 31;
    float Grow[32];
#pragma unroll
    for (int j = 0; j < 32; ++j) Grow[j] = Gw[r * 33 + j];
    const float inv_  = 1.0f / fmaxf(sqrtf(Gw[r * 33 + r]), 1e-12f);
    const float inv32 = inv_ * (1.0f / 32.0f);

    // ---- Phase 3: mu0 = normalize(mean(Xn)):  alpha'_j = inv_j/32, then scale
    float a = inv32;
    float ga;
    {
        float s0 = 0, s1 = 0, s2 = 0, s3 = 0;
#pragma unroll
        for (int j = 0; j < 8; ++j) {
            s0 = fmaf(Grow[j],      rl(a, j),      s0);
            s1 = fmaf(Grow[j + 8],  rl(a, j + 8),  s1);
            s2 = fmaf(Grow[j + 16], rl(a, j + 16), s2);
            s3 = fmaf(Grow[j + 24], rl(a, j + 24), s3);
        }
        ga = (s0 + s1) + (s2 + s3);
        float n2   = rowsum32(a * ga);
        float inv0 = 1.0f / fmaxf(sqrtf(n2), 1e-12f);
        a  *= inv0;
        ga *= inv0;
    }

    // ---- Phase 4: Karcher iterations (raw-G space) --------------------------
    for (int it = 0; it < MAX_ITERS; ++it) {
        float dotr = ga * inv_;                   // dots_r (unclipped)
        float x  = fminf(fmaxf(dotr, -1.0f + CLIPV), 1.0f - CLIPV);
        float th = fast_acos(x);
        float st = fmaxf(sqrtf(fmaxf(1.0f - x * x, 0.0f)), EPSV);
        float w  = __fdividef(th, st);
        float u  = w * inv32;                     // v = G u - (C/32) G alpha'
        // matvec G*u is independent of C -> overlaps rowsum(C)
        float s0 = 0, s1 = 0, s2 = 0, s3 = 0;
#pragma unroll
        for (int j = 0; j < 8; ++j) {
            s0 = fmaf(Grow[j],      rl(u, j),      s0);
            s1 = fmaf(Grow[j + 8],  rl(u, j + 8),  s1);
            s2 = fmaf(Grow[j + 16], rl(u, j + 16), s2);
            s3 = fmaf(Grow[j + 24], rl(u, j + 24), s3);
        }
        float gu  = (s0 + s1) + (s2 + s3);
        float C   = rowsum32(w * dotr);           // sum_n w_n dot_n
        float c32 = C * (1.0f / 32.0f);
        float beta = u  - c32 * a;                // beta' (raw-coeff v)
        float gb   = gu - c32 * ga;               // (G beta')_r
        float vv = rowsum32(beta * gb);           // ||v||^2
        float vs = fmaxf(sqrtf(fmaxf(vv, 0.0f)), EPSV);
        float cv = __cosf(vs);
        float sv = __fdividef(__sinf(vs), vs);
        a  = fmaf(sv, beta, cv * a);              // exp map (v perp mu)
        ga = fmaf(sv, gb, cv * ga);
        if (vs < 1e-6f) break;  // wave-uniform; drift vs ref < 2e-5 in mu
    }

    // ---- Phase 5: per-group partial loss, one plain store per wave ----------
    float xf = fminf(fmaxf(ga * inv_, -1.0f + CLIPV), 1.0f - CLIPV);
    float t  = fast_acos(xf);
    float ls = rowsum32(t * t);   // wave-uniform
    if (lane == 0) ws[blockIdx.x * 2 + wid] = ls;
}

__global__ void __launch_bounds__(256) reduce_partials(const float* __restrict__ ws,
                                                       float* __restrict__ out,
                                                       int n, float scale) {
    __shared__ float sred[4];
    float s = 0.f;
    for (int i = threadIdx.x; i < n; i += 256) s += ws[i];
#pragma unroll
    for (int m = 32; m >= 1; m >>= 1) s += __shfl_xor(s, m, 64);
    const int lane = threadIdx.x & 63, wid = threadIdx.x >> 6;
    if (lane == 0) sred[wid] = s;
    __syncthreads();
    if (threadIdx.x == 0)
        out[0] = ((sred[0] + sred[1]) + (sred[2] + sred[3])) * scale;
}

extern "C" void kernel_launch(void* const* d_in, const int* in_sizes, int n_in,
                              void* d_out, int out_size, void* d_ws, size_t ws_size,
                              hipStream_t stream) {
    const float* X = (const float*)d_in[0];
    float* out = (float*)d_out;
    float* ws = (float*)d_ws;
    int n_groups = in_sizes[0] / (32 * 128);   // 8000
    int blocks = n_groups / 2;                 // 4000 blocks, 2 waves each
    karcher<<<blocks, 128, 0, stream>>>(X, ws, n_groups);
    reduce_partials<<<1, 256, 0, stream>>>(ws, out, n_groups, 1.0f / (float)n_groups);
}

// Round 6
// 215.941 us; speedup vs baseline: 1.0620x; 1.0620x over previous
//
#include <hip/hip_runtime.h>
#include <stdint.h>

#define MAX_ITERS 20
#define EPSV 1e-7f
#define CLIPV 1e-7f
#define PI_F 3.14159265358979f
#define PIO2_F 1.57079632679490f
#define SGS 36   // Gram LDS row stride in floats: 16B-aligned rows for ds_read_b128

typedef __attribute__((ext_vector_type(8))) short short8;
typedef __attribute__((ext_vector_type(4))) float f4;

__device__ __forceinline__ f4 mfma_bf16(short8 a, short8 b, f4 c) {
    return __builtin_amdgcn_mfma_f32_16x16x32_bf16(a, b, c, 0, 0, 0);
}

// DPP-routed add: v += v[lane ^ k] within 16-lane rows (VALU pipe)
template <int CTRL>
__device__ __forceinline__ float dpp_add(float v) {
    int p = __builtin_amdgcn_update_dpp(0, __float_as_int(v), CTRL, 0xF, 0xF, true);
    return v + __int_as_float(p);
}

// Sum over each 32-lane half independently; result uniform within each half.
__device__ __forceinline__ float halfsum32(float v) {
    v = dpp_add<0xB1>(v);   // xor1  (quad_perm)
    v = dpp_add<0x4E>(v);   // xor2  (quad_perm)
    v = dpp_add<0x141>(v);  // xor4  (row_half_mirror)
    v = dpp_add<0x140>(v);  // xor8  (row_mirror)
    // xor16 within each 32-lane group: ds_swizzle bit-mode, and=0x1F xor=0x10
    v += __int_as_float(
        __builtin_amdgcn_ds_swizzle(__float_as_int(v), 0x401F));
    return v;
}

// Branchless acos, |err| ~1e-7; input pre-clipped to (-1, 1).
__device__ __forceinline__ float fast_acos(float x) {
    float a = fabsf(x);
    bool big = a > 0.5f;
    float z = big ? 0.5f * (1.0f - a) : x * x;
    float s = big ? sqrtf(z) : x;
    float p = fmaf(z, fmaf(z, fmaf(z, fmaf(z, 4.2163199048e-2f, 2.4181311049e-2f),
                                   4.5470025998e-2f), 7.4953002686e-2f),
                   1.6666752422e-1f);
    float r = fmaf(s * z, p, s);    // asin(s), |s| <= 0.5
    float big_val = (x < 0.0f) ? (PI_F - 2.0f * r) : (2.0f * r);
    return big ? big_val : (PIO2_F - r);
}

// split 8 fp32 -> truncated-bf16 hi + bf16(lo) residual
__device__ __forceinline__ void cvt_hilo(const float* v, short8& hi, short8& lo) {
#pragma unroll
    for (int i = 0; i < 8; ++i) {
        float x = v[i];
        uint32_t u = __float_as_uint(x);
        float hf = __uint_as_float(u & 0xFFFF0000u);
        float lf = x - hf;
        hi[i] = (short)(u >> 16);
        lo[i] = (short)(__float_as_uint(lf) >> 16);
    }
}

// 256 thr = 4 waves/block; each wave owns TWO groups (lanes 0-31 / 32-63).
// 1000 blocks, 37.9 KB LDS -> 4 blocks/CU -> entire grid co-resident.
// min 4 waves/EU -> VGPR cap 128: Grow[32]+state stays register-resident.
__global__ void __launch_bounds__(256, 4) karcher(const float* __restrict__ X,
                                                  float* __restrict__ ws) {
    __shared__ float sG[8][32 * SGS];   // raw Grams, one per (wave,half)
    __shared__ float sU[8][32];         // per-iter broadcast buffer

    const int lane = threadIdx.x & 63;
    const int wid  = threadIdx.x >> 6;
    const int half = lane >> 5;         // which of the wave's two groups
    const int r    = lane & 31;         // this lane's row within its group
    const int slot = wid * 2;
    const int g0   = blockIdx.x * 8 + wid * 2;

    const int col  = lane & 15;
    const int quad = lane >> 4;

    // ---- Phase 1: raw Gram for BOTH groups (whole wave per group) -----------
#pragma unroll
    for (int h = 0; h < 2; ++h) {
        const float* Xg = X + (size_t)(g0 + h) * (32 * 128);
        f4 acc00 = {0.f, 0.f, 0.f, 0.f};
        f4 acc01 = acc00, acc10 = acc00, acc11 = acc00;
#pragma unroll
        for (int kc = 0; kc < 4; ++kc) {
            const float* p0 = Xg + col * 128 + kc * 32 + quad * 8;
            const float* p1 = p0 + 16 * 128;
            float r0[8], r1[8];
            *(float4*)(r0)     = *(const float4*)(p0);
            *(float4*)(r0 + 4) = *(const float4*)(p0 + 4);
            *(float4*)(r1)     = *(const float4*)(p1);
            *(float4*)(r1 + 4) = *(const float4*)(p1 + 4);
            short8 H0, L0, H1, L1;
            cvt_hilo(r0, H0, L0);
            cvt_hilo(r1, H1, L1);
            acc00 = mfma_bf16(H0, H0, acc00);
            acc00 = mfma_bf16(H0, L0, acc00);
            acc00 = mfma_bf16(L0, H0, acc00);
            acc01 = mfma_bf16(H0, H1, acc01);
            acc01 = mfma_bf16(H0, L1, acc01);
            acc01 = mfma_bf16(L0, H1, acc01);
            acc10 = mfma_bf16(H1, H0, acc10);
            acc10 = mfma_bf16(H1, L0, acc10);
            acc10 = mfma_bf16(L1, H0, acc10);
            acc11 = mfma_bf16(H1, H1, acc11);
            acc11 = mfma_bf16(H1, L1, acc11);
            acc11 = mfma_bf16(L1, H1, acc11);
        }
        float* Gh = sG[slot + h];
#pragma unroll
        for (int i = 0; i < 4; ++i) {   // C/D: col=lane&15, row=quad*4+i (G sym)
            int rw = quad * 4 + i;
            Gh[rw * SGS + col]             = acc00[i];
            Gh[rw * SGS + col + 16]        = acc01[i];
            Gh[(rw + 16) * SGS + col]      = acc10[i];
            Gh[(rw + 16) * SGS + col + 16] = acc11[i];
        }
    }
    // No __syncthreads: each wave reads back only what it wrote (lgkmcnt orders)

    // ---- Phase 2: own raw Gram row -> VGPRs; own inverse norm ---------------
    float* Gw = sG[slot + half];
    float Grow[32];
#pragma unroll
    for (int c = 0; c < 8; ++c)
        *(float4*)(&Grow[c * 4]) = *(const float4*)(&Gw[r * SGS + c * 4]);
    const float inv_  = 1.0f / fmaxf(sqrtf(Gw[r * SGS + r]), 1e-12f);
    const float inv32 = inv_ * (1.0f / 32.0f);

    float* sUrow = sU[slot + half];
    const float4* ub = (const float4*)sUrow;

    // matvec: broadcast uval across the half via LDS, dot with Grow
#define MATVEC(uval, guout)                                                  \
    {                                                                        \
        sUrow[r] = (uval);                                                   \
        float m0 = 0, m1 = 0, m2 = 0, m3 = 0;                                \
        _Pragma("unroll") for (int c = 0; c < 8; ++c) {                      \
            float4 uc = ub[c];                                               \
            float* mp = (c & 1) ? ((c & 2) ? &m3 : &m1)                      \
                                : ((c & 2) ? &m2 : &m0);                     \
            *mp = fmaf(Grow[4 * c + 3], uc.w,                                \
                  fmaf(Grow[4 * c + 2], uc.z,                                \
                  fmaf(Grow[4 * c + 1], uc.y,                                \
                  fmaf(Grow[4 * c + 0], uc.x, *mp))));                       \
        }                                                                    \
        (guout) = (m0 + m1) + (m2 + m3);                                     \
    }

    // ---- Phase 3: mu0 = normalize(mean(Xn)) in raw-coefficient space --------
    float a = inv32;     // alpha'_r
    float ga;            // (G alpha')_r
    MATVEC(a, ga);
    {
        float n2   = halfsum32(a * ga);
        float inv0 = 1.0f / fmaxf(sqrtf(n2), 1e-12f);
        a  *= inv0;
        ga *= inv0;
    }

    // ---- Phase 4: Karcher iterations (each half = one group) ----------------
    for (int it = 0; it < MAX_ITERS; ++it) {
        float dotr = ga * inv_;
        float x  = fminf(fmaxf(dotr, -1.0f + CLIPV), 1.0f - CLIPV);
        float th = fast_acos(x);
        float st = fmaxf(sqrtf(fmaxf(1.0f - x * x, 0.0f)), EPSV);
        float w  = __fdividef(th, st);
        float u  = w * inv32;
        float gu;
        MATVEC(u, gu);
        float c    = halfsum32(u * ga);       // = (1/32) sum_n w_n dot_n
        float beta = u  - c * a;
        float gb   = gu - c * ga;
        float vv = halfsum32(beta * gb);      // ||v||^2 (no cancellation)
        float vs = fmaxf(sqrtf(fmaxf(vv, 0.0f)), EPSV);
        float cv = __cosf(vs);
        float sv = __fdividef(__sinf(vs), vs);
        a  = fmaf(sv, beta, cv * a);          // exp map (v perp mu)
        ga = fmaf(sv, gb, cv * ga);
        if (__all(vs < 1e-6f)) break;         // both halves converged
    }

    // ---- Phase 5: per-group loss, one plain store per half ------------------
    float xf = fminf(fmaxf(ga * inv_, -1.0f + CLIPV), 1.0f - CLIPV);
    float t  = fast_acos(xf);
    float ls = halfsum32(t * t);   // uniform within each half
    if (r == 0) ws[g0 + half] = ls;
#undef MATVEC
}

__global__ void __launch_bounds__(256) reduce_partials(const float* __restrict__ ws,
                                                       float* __restrict__ out,
                                                       int n, float scale) {
    __shared__ float sred[4];
    float s = 0.f;
    for (int i = threadIdx.x; i < n; i += 256) s += ws[i];
#pragma unroll
    for (int m = 32; m >= 1; m >>= 1) s += __shfl_xor(s, m, 64);
    const int lane = threadIdx.x & 63, wid = threadIdx.x >> 6;
    if (lane == 0) sred[wid] = s;
    __syncthreads();
    if (threadIdx.x == 0)
        out[0] = ((sred[0] + sred[1]) + (sred[2] + sred[3])) * scale;
}

extern "C" void kernel_launch(void* const* d_in, const int* in_sizes, int n_in,
                              void* d_out, int out_size, void* d_ws, size_t ws_size,
                              hipStream_t stream) {
    const float* X = (const float*)d_in[0];
    float* out = (float*)d_out;
    float* ws = (float*)d_ws;
    int n_groups = in_sizes[0] / (32 * 128);   // 8000
    int blocks = n_groups / 8;                 // 1000 blocks, 8 groups each
    karcher<<<blocks, 256, 0, stream>>>(X, ws);
    reduce_partials<<<1, 256, 0, stream>>>(ws, out, n_groups, 1.0f / (float)n_groups);
}